// Round 1
// baseline (763.401 us; speedup 1.0000x reference)
//
#include <hip/hip_runtime.h>
#include <hip/hip_bf16.h>
#include <math.h>

#define NCLS 81
#define NANCH 8732
#define NB 64
#define TILE_A 64              // anchors per block in conf kernel
#define TILE_FLOATS (TILE_A * NCLS)   // 5184 floats = 1296 float4

// ---------------- Kernel A: per-anchor conf loss + global num_pos ----------------
// grid = 8732 blocks (64*8732/64), block = 256 threads (4 lanes per anchor)
__global__ __launch_bounds__(256) void conf_kernel(
    const float* __restrict__ pred_conf,
    const float* __restrict__ gt_conf,
    float* __restrict__ val_out,     // [B*N] signed conf_loss: negative => positive anchor
    int* __restrict__ num_pos)
{
    __shared__ float sp[TILE_FLOATS];
    __shared__ float sg[TILE_FLOATS];
    const int tid = threadIdx.x;
    const long long tile = blockIdx.x;
    const long long base = tile * (long long)TILE_FLOATS;

    // coalesced float4 staging (tile byte offset = 20736*tile, 16B aligned)
    const float4* p4 = (const float4*)(pred_conf + base);
    const float4* g4 = (const float4*)(gt_conf + base);
    float4* sp4 = (float4*)sp;
    float4* sg4 = (float4*)sg;
#pragma unroll
    for (int i = 0; i < 6; ++i) {
        int idx = tid + i * 256;
        if (idx < TILE_FLOATS / 4) {
            sp4[idx] = p4[idx];
            sg4[idx] = g4[idx];
        }
    }
    __syncthreads();

    const int a = tid >> 2;       // anchor within tile, 0..63
    const int q = tid & 3;        // lane group 0..3 (partners in same wave)
    const float* xrow = sp + a * NCLS;
    const float* grow = sg + a * NCLS;

    float x[21];
    float m = -INFINITY;
#pragma unroll
    for (int j = 0; j < 21; ++j) {
        int c = q + 4 * j;
        x[j] = (c < NCLS) ? xrow[c] : -INFINITY;
        m = fmaxf(m, x[j]);
    }
    m = fmaxf(m, __shfl_xor(m, 1));
    m = fmaxf(m, __shfl_xor(m, 2));

    float s = 0.f;
#pragma unroll
    for (int j = 0; j < 21; ++j) {
        int c = q + 4 * j;
        if (c < NCLS) s += expf(x[j] - m);
    }
    s += __shfl_xor(s, 1);
    s += __shfl_xor(s, 2);
    const float lse = m + logf(s);

    float dot = 0.f;
#pragma unroll
    for (int j = 0; j < 21; ++j) {
        int c = q + 4 * j;
        if (c < NCLS) dot += (x[j] - lse) * grow[c];
    }
    dot += __shfl_xor(dot, 1);
    dot += __shfl_xor(dot, 2);
    const float conf_loss = -dot;

    bool pos = false;
    if (q == 0) {
        pos = (grow[0] == 0.0f);   // one-hot background prob == 0 => positive
        val_out[tile * TILE_A + a] = pos ? -conf_loss : conf_loss;
    }
    unsigned long long mb = __ballot(pos);   // only q==0 lanes can be true
    if ((tid & 63) == 0)
        atomicAdd(num_pos, (int)__popcll(mb));
}

// ---------------- Kernel L: smooth-L1-quirk loc loss ----------------
// grid = (35, 64), block = 256; one float4 (one anchor's 4 coords) per thread
__global__ __launch_bounds__(256) void loc_kernel(
    const float* __restrict__ pred_loc,
    const float* __restrict__ gt_loc,
    float* __restrict__ out)   // out[64+b] accumulated atomically (pre-zeroed)
{
    __shared__ float red[4];
    const int b = blockIdx.y;
    const int idx = blockIdx.x * 256 + threadIdx.x;   // float4 index, 8732 per row
    float local = 0.f;
    if (idx < NANCH) {
        const float4* p = (const float4*)(pred_loc + (long long)b * (NANCH * 4));
        const float4* g = (const float4*)(gt_loc + (long long)b * (NANCH * 4));
        float4 pv = p[idx];
        float4 gv = g[idx];
        float d0 = pv.x - gv.x, d1 = pv.y - gv.y, d2 = pv.z - gv.z, d3 = pv.w - gv.w;
        float a0 = fabsf(d0), a1 = fabsf(d1), a2 = fabsf(d2), a3 = fabsf(d3);
        local  = (a0 > 1.f) ? (a0 - 0.5f) : 0.f;
        local += (a1 > 1.f) ? (a1 - 0.5f) : 0.f;
        local += (a2 > 1.f) ? (a2 - 0.5f) : 0.f;
        local += (a3 > 1.f) ? (a3 - 0.5f) : 0.f;
    }
    // wave64 butterfly then block reduce
    for (int off = 32; off; off >>= 1) local += __shfl_xor(local, off);
    if ((threadIdx.x & 63) == 0) red[threadIdx.x >> 6] = local;
    __syncthreads();
    if (threadIdx.x == 0)
        atomicAdd(&out[64 + b], red[0] + red[1] + red[2] + red[3]);
}

// ---------------- Kernel B: hard-negative mining + conf total ----------------
// grid = 64 (one block per batch row), block = 256
__global__ __launch_bounds__(256) void select_kernel(
    const float* __restrict__ val,
    const int* __restrict__ num_pos_p,
    float* __restrict__ out)
{
    __shared__ float cl[NANCH];          // 34928 B
    __shared__ int hist[256];
    __shared__ int scnt[256];
    __shared__ unsigned int sh_prefix;
    __shared__ int sh_k, sh_thr, sh_chosen, sh_before;
    __shared__ float red[4];

    const int b = blockIdx.x;
    const int tid = threadIdx.x;
    const float* row = val + (long long)b * NANCH;

    float pos_local = 0.f;
    for (int i = tid; i < NANCH; i += 256) {
        float v = row[i];
        cl[i] = fmaxf(v, 0.0f);          // cl_neg (positives encoded negative -> 0)
        if (v < 0.f) pos_local -= v;     // positive conf loss contribution
    }
    __syncthreads();

    int k = 3 * (*num_pos_p);            // global num_neg (ref: int(3.0*num_pos))
    if (k > NANCH - 1) k = NANCH - 1;
    if (k < 0) k = 0;

    // radix select rank-k ascending on float bits (all values >= 0 -> monotone)
    unsigned int prefix = 0u;
    for (int r = 0; r < 4; ++r) {
        const int shift = 24 - 8 * r;
        const unsigned int maskHigh = (r == 0) ? 0u : (0xFFFFFFFFu << (shift + 8));
        hist[tid] = 0;
        __syncthreads();
        for (int i = tid; i < NANCH; i += 256) {
            unsigned int u = __float_as_uint(cl[i]);
            if ((u & maskHigh) == prefix)
                atomicAdd(&hist[(u >> shift) & 0xFF], 1);
        }
        __syncthreads();
        if (tid == 0) {
            int cum = 0, g = 0;
            for (; g < 256; ++g) {
                if (cum + hist[g] > k) break;
                cum += hist[g];
            }
            sh_prefix = prefix | ((unsigned int)g << shift);
            sh_k = k - cum;
        }
        __syncthreads();
        prefix = sh_prefix;
        k = sh_k;
        __syncthreads();
    }
    const unsigned int T = prefix;       // target key; k = residual rank among equals

    // stable (index-order) resolution of the k-th equal element -> its anchor index
    const int CHUNK = (NANCH + 255) / 256;   // 35
    const int lo = tid * CHUNK;
    const int hi = (lo + CHUNK < NANCH) ? (lo + CHUNK) : NANCH;
    int cnt = 0;
    for (int i = lo; i < hi; ++i)
        if (__float_as_uint(cl[i]) == T) ++cnt;
    scnt[tid] = cnt;
    __syncthreads();
    if (tid == 0) {
        int cum = 0, t = 0;
        for (; t < 256; ++t) {
            if (cum + scnt[t] > k) break;
            cum += scnt[t];
        }
        sh_chosen = t;
        sh_before = cum;
    }
    __syncthreads();
    if (tid == sh_chosen) {
        int need = k - sh_before, idx = NANCH - 1;
        for (int i = lo; i < hi; ++i) {
            if (__float_as_uint(cl[i]) == T) {
                if (need == 0) { idx = i; break; }
                --need;
            }
        }
        sh_thr = idx;
    }
    __syncthreads();

    const float thr = (float)sh_thr;     // the quirk: threshold is the INDEX as float
    float local = pos_local;
    for (int i = tid; i < NANCH; i += 256) {
        float c = cl[i];
        if (c > thr) local += c;         // negatives kept by mining
    }
    for (int off = 32; off; off >>= 1) local += __shfl_xor(local, off);
    if ((tid & 63) == 0) red[tid >> 6] = local;
    __syncthreads();
    if (tid == 0) out[b] = red[0] + red[1] + red[2] + red[3];
}

extern "C" void kernel_launch(void* const* d_in, const int* in_sizes, int n_in,
                              void* d_out, int out_size, void* d_ws, size_t ws_size,
                              hipStream_t stream) {
    const float* pred_conf = (const float*)d_in[0];
    const float* pred_loc  = (const float*)d_in[1];
    const float* gt_conf   = (const float*)d_in[2];
    const float* gt_loc    = (const float*)d_in[3];
    float* out = (float*)d_out;

    int*   num_pos = (int*)d_ws;
    float* vals    = (float*)((char*)d_ws + 256);   // [64*8732] floats

    hipMemsetAsync(d_ws, 0, 256, stream);                       // zero num_pos
    hipMemsetAsync(d_out, 0, 128 * sizeof(float), stream);      // zero outputs (loc uses atomics)

    conf_kernel<<<NB * NANCH / TILE_A, 256, 0, stream>>>(pred_conf, gt_conf, vals, num_pos);
    loc_kernel<<<dim3((NANCH + 255) / 256, NB), 256, 0, stream>>>(pred_loc, gt_loc, out);
    select_kernel<<<NB, 256, 0, stream>>>(vals, num_pos, out);
}

// Round 2
// 427.645 us; speedup vs baseline: 1.7851x; 1.7851x over previous
//
#include <hip/hip_runtime.h>
#include <hip/hip_bf16.h>
#include <math.h>

#define NCLS 81
#define NANCH 8732
#define NB 64
#define TILE_A 64                     // anchors per block in conf kernel
#define TILE_FLOATS (TILE_A * NCLS)   // 5184 floats = 1296 float4
#define NBUCKET 64                    // num_pos atomic buckets (cacheline-spread)
#define BUCKET_STRIDE 16              // 16 ints = 64 B

// ---------------- Kernel A: per-anchor conf loss + bucketed num_pos ----------------
// grid = 8732 blocks, block = 256 threads (4 lanes per anchor)
__global__ __launch_bounds__(256) void conf_kernel(
    const float* __restrict__ pred_conf,
    const float* __restrict__ gt_conf,
    float* __restrict__ val_out,     // [B*N] signed conf_loss: negative => positive anchor
    int* __restrict__ pos_buckets)   // [NBUCKET * BUCKET_STRIDE], pre-zeroed
{
    __shared__ float sp[TILE_FLOATS];
    __shared__ float sg[TILE_FLOATS];
    __shared__ int pcnt[4];
    const int tid = threadIdx.x;
    const long long tile = blockIdx.x;
    const long long base = tile * (long long)TILE_FLOATS;

    // coalesced float4 staging (tile byte offset = 20736*tile, 16B aligned)
    const float4* p4 = (const float4*)(pred_conf + base);
    const float4* g4 = (const float4*)(gt_conf + base);
    float4* sp4 = (float4*)sp;
    float4* sg4 = (float4*)sg;
#pragma unroll
    for (int i = 0; i < 6; ++i) {
        int idx = tid + i * 256;
        if (idx < TILE_FLOATS / 4) {
            sp4[idx] = p4[idx];
            sg4[idx] = g4[idx];
        }
    }
    __syncthreads();

    const int a = tid >> 2;       // anchor within tile, 0..63
    const int q = tid & 3;        // lane group 0..3 (partners in same wave)
    const float* xrow = sp + a * NCLS;
    const float* grow = sg + a * NCLS;

    float x[21];
    float m = -INFINITY;
#pragma unroll
    for (int j = 0; j < 21; ++j) {
        int c = q + 4 * j;
        x[j] = (c < NCLS) ? xrow[c] : -INFINITY;
        m = fmaxf(m, x[j]);
    }
    m = fmaxf(m, __shfl_xor(m, 1));
    m = fmaxf(m, __shfl_xor(m, 2));

    float s = 0.f;
#pragma unroll
    for (int j = 0; j < 21; ++j) {
        int c = q + 4 * j;
        if (c < NCLS) s += expf(x[j] - m);
    }
    s += __shfl_xor(s, 1);
    s += __shfl_xor(s, 2);
    const float lse = m + logf(s);

    float dot = 0.f;
#pragma unroll
    for (int j = 0; j < 21; ++j) {
        int c = q + 4 * j;
        if (c < NCLS) dot += (x[j] - lse) * grow[c];
    }
    dot += __shfl_xor(dot, 1);
    dot += __shfl_xor(dot, 2);
    const float conf_loss = -dot;

    bool pos = false;
    if (q == 0) {
        pos = (grow[0] == 0.0f);   // one-hot background prob == 0 => positive
        val_out[tile * TILE_A + a] = pos ? -conf_loss : conf_loss;
    }
    unsigned long long mb = __ballot(pos);   // only q==0 lanes can be true
    if ((tid & 63) == 0) pcnt[tid >> 6] = (int)__popcll(mb);
    __syncthreads();
    if (tid == 0) {
        int tot = pcnt[0] + pcnt[1] + pcnt[2] + pcnt[3];
        if (tot)
            atomicAdd(&pos_buckets[(blockIdx.x & (NBUCKET - 1)) * BUCKET_STRIDE], tot);
    }
}

// ---------------- Kernel L: smooth-L1-quirk loc loss ----------------
// grid = (35, 64), block = 256; one float4 (one anchor's 4 coords) per thread
__global__ __launch_bounds__(256) void loc_kernel(
    const float* __restrict__ pred_loc,
    const float* __restrict__ gt_loc,
    float* __restrict__ out)   // out[64+b] accumulated atomically (pre-zeroed)
{
    __shared__ float red[4];
    const int b = blockIdx.y;
    const int idx = blockIdx.x * 256 + threadIdx.x;   // float4 index, 8732 per row
    float local = 0.f;
    if (idx < NANCH) {
        const float4* p = (const float4*)(pred_loc + (long long)b * (NANCH * 4));
        const float4* g = (const float4*)(gt_loc + (long long)b * (NANCH * 4));
        float4 pv = p[idx];
        float4 gv = g[idx];
        float d0 = pv.x - gv.x, d1 = pv.y - gv.y, d2 = pv.z - gv.z, d3 = pv.w - gv.w;
        float a0 = fabsf(d0), a1 = fabsf(d1), a2 = fabsf(d2), a3 = fabsf(d3);
        local  = (a0 > 1.f) ? (a0 - 0.5f) : 0.f;
        local += (a1 > 1.f) ? (a1 - 0.5f) : 0.f;
        local += (a2 > 1.f) ? (a2 - 0.5f) : 0.f;
        local += (a3 > 1.f) ? (a3 - 0.5f) : 0.f;
    }
    for (int off = 32; off; off >>= 1) local += __shfl_xor(local, off);
    if ((threadIdx.x & 63) == 0) red[threadIdx.x >> 6] = local;
    __syncthreads();
    if (threadIdx.x == 0)
        atomicAdd(&out[64 + b], red[0] + red[1] + red[2] + red[3]);
}

// ---------------- Kernel B: hard-negative mining + conf total ----------------
// grid = 64 (one block per batch row), block = 256
__global__ __launch_bounds__(256) void select_kernel(
    const float* __restrict__ val,
    const int* __restrict__ pos_buckets,
    float* __restrict__ out)
{
    __shared__ float cl[NANCH];          // 34928 B
    __shared__ int hist[256];
    __shared__ int wsum[4];
    __shared__ int sh_numpos;
    __shared__ unsigned int sh_prefix;
    __shared__ int sh_k, sh_thr;
    __shared__ float red[4];

    const int b = blockIdx.x;
    const int tid = threadIdx.x;
    const int lane = tid & 63, w = tid >> 6;
    const float* row = val + (long long)b * NANCH;

    // sum the 64 num_pos buckets (wave 0 only)
    if (tid < 64) {
        int v = pos_buckets[tid * BUCKET_STRIDE];
        for (int off = 32; off; off >>= 1) v += __shfl_xor(v, off);
        if (tid == 0) sh_numpos = v;
    }

    float pos_local = 0.f;
    for (int i = tid; i < NANCH; i += 256) {
        float v = row[i];
        cl[i] = fmaxf(v, 0.0f);          // cl_neg (positives encoded negative -> 0)
        if (v < 0.f) pos_local -= v;     // positive conf loss contribution
    }
    __syncthreads();

    int k = 3 * sh_numpos;               // global num_neg (ref: int(3.0*num_pos))
    if (k > NANCH - 1) k = NANCH - 1;
    if (k < 0) k = 0;

    // radix select rank-k ascending on float bits (all values >= 0 -> monotone)
    unsigned int prefix = 0u;
    for (int r = 0; r < 4; ++r) {
        const int shift = 24 - 8 * r;
        const unsigned int maskHigh = (r == 0) ? 0u : (0xFFFFFFFFu << (shift + 8));
        hist[tid] = 0;
        __syncthreads();
        for (int i = tid; i < NANCH; i += 256) {
            unsigned int u = __float_as_uint(cl[i]);
            if ((u & maskHigh) == prefix)
                atomicAdd(&hist[(u >> shift) & 0xFF], 1);
        }
        __syncthreads();
        // parallel block scan over 256 bins: wave64 inclusive scan + wave offsets
        int h = hist[tid];
        int v = h;
#pragma unroll
        for (int off = 1; off < 64; off <<= 1) {
            int u2 = __shfl_up(v, off);
            if (lane >= off) v += u2;
        }
        if (lane == 63) wsum[w] = v;
        __syncthreads();
        int add = 0;
        for (int i = 0; i < w; ++i) add += wsum[i];
        int incl = v + add, excl = incl - h;
        if (excl <= k && k < incl) {
            sh_prefix = prefix | ((unsigned int)tid << shift);
            sh_k = k - excl;
        }
        __syncthreads();
        prefix = sh_prefix;
        k = sh_k;
        __syncthreads();
    }
    const unsigned int T = prefix;       // target key; k = residual rank among equals

    // stable (index-order) resolution of the k-th equal element -> its anchor index
    const int CHUNK = (NANCH + 255) / 256;   // 35
    const int lo = tid * CHUNK;
    const int hi = (lo + CHUNK < NANCH) ? (lo + CHUNK) : NANCH;
    int cnt = 0;
    for (int i = lo; i < hi; ++i)
        if (__float_as_uint(cl[i]) == T) ++cnt;
    // parallel scan of per-thread counts
    {
        int v = cnt;
#pragma unroll
        for (int off = 1; off < 64; off <<= 1) {
            int u2 = __shfl_up(v, off);
            if (lane >= off) v += u2;
        }
        if (lane == 63) wsum[w] = v;
        __syncthreads();
        int add = 0;
        for (int i = 0; i < w; ++i) add += wsum[i];
        int incl = v + add, excl = incl - cnt;
        if (excl <= k && k < incl) {
            int need = k - excl, idx = NANCH - 1;
            for (int i = lo; i < hi; ++i) {
                if (__float_as_uint(cl[i]) == T) {
                    if (need == 0) { idx = i; break; }
                    --need;
                }
            }
            sh_thr = idx;
        }
        __syncthreads();
    }

    const float thr = (float)sh_thr;     // the quirk: threshold is the INDEX as float
    float local = pos_local;
    for (int i = tid; i < NANCH; i += 256) {
        float c = cl[i];
        if (c > thr) local += c;         // negatives kept by mining
    }
    for (int off = 32; off; off >>= 1) local += __shfl_xor(local, off);
    if ((tid & 63) == 0) red[tid >> 6] = local;
    __syncthreads();
    if (tid == 0) out[b] = red[0] + red[1] + red[2] + red[3];
}

extern "C" void kernel_launch(void* const* d_in, const int* in_sizes, int n_in,
                              void* d_out, int out_size, void* d_ws, size_t ws_size,
                              hipStream_t stream) {
    const float* pred_conf = (const float*)d_in[0];
    const float* pred_loc  = (const float*)d_in[1];
    const float* gt_conf   = (const float*)d_in[2];
    const float* gt_loc    = (const float*)d_in[3];
    float* out = (float*)d_out;

    int*   pos_buckets = (int*)d_ws;                  // 64 buckets * 64B = 4 KB
    float* vals        = (float*)((char*)d_ws + 8192);   // [64*8732] floats

    hipMemsetAsync(d_ws, 0, 8192, stream);                      // zero buckets
    hipMemsetAsync(d_out, 0, 128 * sizeof(float), stream);      // zero outputs (loc uses atomics)

    conf_kernel<<<NB * NANCH / TILE_A, 256, 0, stream>>>(pred_conf, gt_conf, vals, pos_buckets);
    loc_kernel<<<dim3((NANCH + 255) / 256, NB), 256, 0, stream>>>(pred_loc, gt_loc, out);
    select_kernel<<<NB, 256, 0, stream>>>(vals, pos_buckets, out);
}

// Round 3
// 404.283 us; speedup vs baseline: 1.8883x; 1.0578x over previous
//
#include <hip/hip_runtime.h>
#include <hip/hip_bf16.h>
#include <math.h>

#define NCLS 81
#define NANCH 8732
#define NB 64
#define BUCKET_STRIDE 16   // 64 B cacheline spread for int buckets

// ---------------- Kernel A: per-anchor conf loss, no LDS ----------------
// grid = 8732 blocks x 256 threads; 4 lanes per anchor (64 anchors/block)
__global__ __launch_bounds__(256) void conf_kernel(
    const float* __restrict__ pred_conf,
    const float* __restrict__ gt_conf,
    float* __restrict__ cl_out,       // [B*N] cl_neg: conf_loss for negatives, 0 for positives
    int* __restrict__ pos_buckets,    // [64*BUCKET_STRIDE] ints, pre-zeroed
    float* __restrict__ row_pos)      // [64] per-row positive-loss sums, pre-zeroed
{
    const int tid = threadIdx.x;
    const int anchor = blockIdx.x * 64 + (tid >> 2);   // 0..558847
    const int q = tid & 3;                             // lane within cluster
    const float* xrow = pred_conf + (size_t)anchor * NCLS;
    const float* grow = gt_conf + (size_t)anchor * NCLS;

    // pass 1: load this lane's 21 strided elements, running max
    float x[21];
    float m = -INFINITY;
#pragma unroll
    for (int j = 0; j < 21; ++j) {
        int c = q + 4 * j;
        x[j] = (c < NCLS) ? xrow[c] : -INFINITY;
        m = fmaxf(m, x[j]);
    }
    m = fmaxf(m, __shfl_xor(m, 1));
    m = fmaxf(m, __shfl_xor(m, 2));

    // pass 2: exp-sum from registers
    float s = 0.f;
#pragma unroll
    for (int j = 0; j < 21; ++j) {
        int c = q + 4 * j;
        if (c < NCLS) s += expf(x[j] - m);
    }
    s += __shfl_xor(s, 1);
    s += __shfl_xor(s, 2);
    const float lse = m + logf(s);

    // pass 3: dot with one-hot gt (read gt once), capture gt[...,0]
    float dot = 0.f, g0 = 1.f;
#pragma unroll
    for (int j = 0; j < 21; ++j) {
        int c = q + 4 * j;
        if (c < NCLS) {
            float g = grow[c];
            if (c == 0) g0 = g;          // only q==0, j==0
            dot = fmaf(g, x[j] - lse, dot);
        }
    }
    dot += __shfl_xor(dot, 1);
    dot += __shfl_xor(dot, 2);
    const float conf_loss = -dot;

    const bool posf = (q == 0) && (g0 == 0.0f);  // background prob == 0 => positive
    if (q == 0) cl_out[anchor] = posf ? 0.0f : conf_loss;

    // per-row positive sums (wave straddles at most 2 rows) + global pos count
    const int b = anchor / NANCH;
    const float contrib = posf ? conf_loss : 0.0f;
    const int bF = __builtin_amdgcn_readfirstlane(b);
    float c0 = (b == bF) ? contrib : 0.0f;
    float c1 = contrib - c0;
    for (int off = 32; off; off >>= 1) {
        c0 += __shfl_xor(c0, off);
        c1 += __shfl_xor(c1, off);
    }
    const int pc = (int)__popcll(__ballot(posf));
    if ((tid & 63) == 0) {
        if (c0 != 0.f) atomicAdd(&row_pos[bF], c0);
        if (c1 != 0.f) atomicAdd(&row_pos[bF + 1], c1);
        if (pc) atomicAdd(&pos_buckets[(blockIdx.x & 63) * BUCKET_STRIDE], pc);
    }
}

// ---------------- Kernel L: smooth-L1-quirk loc loss ----------------
__global__ __launch_bounds__(256) void loc_kernel(
    const float* __restrict__ pred_loc,
    const float* __restrict__ gt_loc,
    float* __restrict__ out)   // out[64+b], pre-zeroed
{
    __shared__ float red[4];
    const int b = blockIdx.y;
    const int idx = blockIdx.x * 256 + threadIdx.x;
    float local = 0.f;
    if (idx < NANCH) {
        const float4* p = (const float4*)(pred_loc + (long long)b * (NANCH * 4));
        const float4* g = (const float4*)(gt_loc + (long long)b * (NANCH * 4));
        float4 pv = p[idx];
        float4 gv = g[idx];
        float a0 = fabsf(pv.x - gv.x), a1 = fabsf(pv.y - gv.y);
        float a2 = fabsf(pv.z - gv.z), a3 = fabsf(pv.w - gv.w);
        local  = (a0 > 1.f) ? (a0 - 0.5f) : 0.f;
        local += (a1 > 1.f) ? (a1 - 0.5f) : 0.f;
        local += (a2 > 1.f) ? (a2 - 0.5f) : 0.f;
        local += (a3 > 1.f) ? (a3 - 0.5f) : 0.f;
    }
    for (int off = 32; off; off >>= 1) local += __shfl_xor(local, off);
    if ((threadIdx.x & 63) == 0) red[threadIdx.x >> 6] = local;
    __syncthreads();
    if (threadIdx.x == 0)
        atomicAdd(&out[64 + b], red[0] + red[1] + red[2] + red[3]);
}

// ---------------- Kernel B: hard-negative mining + conf total ----------------
// grid = 64 rows, block = 1024 threads (16 waves)
__global__ __launch_bounds__(1024) void select_kernel(
    const float* __restrict__ val,        // cl_neg per anchor
    const int* __restrict__ pos_buckets,
    const float* __restrict__ row_pos,
    float* __restrict__ out)
{
    __shared__ float cl[NANCH];          // 34928 B
    __shared__ int hist[256];
    __shared__ int wsum[16];
    __shared__ float fred[16];
    __shared__ int sh_numpos;
    __shared__ unsigned int sh_prefix;
    __shared__ int sh_k, sh_thr;

    const int b = blockIdx.x;
    const int tid = threadIdx.x;
    const int lane = tid & 63, w = tid >> 6;
    const float* row = val + b * NANCH;

    if (tid < 64) {
        int v = pos_buckets[tid * BUCKET_STRIDE];
        for (int off = 32; off; off >>= 1) v += __shfl_xor(v, off);
        if (tid == 0) sh_numpos = v;
    }
    for (int i = tid; i < NANCH; i += 1024) cl[i] = row[i];
    __syncthreads();

    int k = 3 * sh_numpos;               // ref: int(3.0 * num_pos), global scalar
    if (k > NANCH - 1) k = NANCH - 1;
    if (k < 0) k = 0;

    // radix select rank-k ascending on float bits (all >= 0 -> monotone)
    unsigned int prefix = 0u;
    for (int r = 0; r < 4; ++r) {
        const int shift = 24 - 8 * r;
        const unsigned int maskHigh = (r == 0) ? 0u : (0xFFFFFFFFu << (shift + 8));
        if (tid < 256) hist[tid] = 0;
        __syncthreads();
        for (int i = tid; i < NANCH; i += 1024) {
            unsigned int u = __float_as_uint(cl[i]);
            if ((u & maskHigh) == prefix)
                atomicAdd(&hist[(u >> shift) & 0xFF], 1);
        }
        __syncthreads();
        int h = 0, v = 0;
        if (tid < 256) {
            h = hist[tid];
            v = h;
#pragma unroll
            for (int off = 1; off < 64; off <<= 1) {
                int u2 = __shfl_up(v, off);
                if (lane >= off) v += u2;
            }
            if (lane == 63) wsum[w] = v;
        }
        __syncthreads();
        if (tid < 256) {
            int add = 0;
            for (int i = 0; i < w; ++i) add += wsum[i];
            int incl = v + add, excl = incl - h;
            if (excl <= k && k < incl) {
                sh_prefix = prefix | ((unsigned int)tid << shift);
                sh_k = k - excl;
            }
        }
        __syncthreads();
        prefix = sh_prefix;
        k = sh_k;
        __syncthreads();
    }
    const unsigned int T = prefix;

    // stable (index-order) resolution of the k-th equal element
    const int CHUNK = 9;                 // ceil(8732/1024)
    int lo = tid * CHUNK; if (lo > NANCH) lo = NANCH;
    int hi = lo + CHUNK; if (hi > NANCH) hi = NANCH;
    int cnt = 0;
    for (int i = lo; i < hi; ++i)
        cnt += (__float_as_uint(cl[i]) == T);
    int v2 = cnt;
#pragma unroll
    for (int off = 1; off < 64; off <<= 1) {
        int u2 = __shfl_up(v2, off);
        if (lane >= off) v2 += u2;
    }
    if (lane == 63) wsum[w] = v2;
    __syncthreads();
    if (tid < 16) {
        int s = wsum[tid];
#pragma unroll
        for (int off = 1; off < 16; off <<= 1) {
            int u2 = __shfl_up(s, off);
            if (lane >= off) s += u2;
        }
        wsum[tid] = s;                   // inclusive prefix of wave sums
    }
    __syncthreads();
    {
        int add = (w == 0) ? 0 : wsum[w - 1];
        int incl = v2 + add, excl = incl - cnt;
        if (excl <= k && k < incl) {
            int need = k - excl, idx = NANCH - 1;
            for (int i = lo; i < hi; ++i) {
                if (__float_as_uint(cl[i]) == T) {
                    if (need == 0) { idx = i; break; }
                    --need;
                }
            }
            sh_thr = idx;
        }
    }
    __syncthreads();

    const float thr = (float)sh_thr;     // quirk: threshold is the argsort INDEX
    float local = 0.f;
    for (int i = tid; i < NANCH; i += 1024) {
        float c = cl[i];
        if (c > thr) local += c;
    }
    for (int off = 32; off; off >>= 1) local += __shfl_xor(local, off);
    if (lane == 0) fred[w] = local;
    __syncthreads();
    if (tid == 0) {
        float t = row_pos[b];
        for (int i = 0; i < 16; ++i) t += fred[i];
        out[b] = t;
    }
}

extern "C" void kernel_launch(void* const* d_in, const int* in_sizes, int n_in,
                              void* d_out, int out_size, void* d_ws, size_t ws_size,
                              hipStream_t stream) {
    const float* pred_conf = (const float*)d_in[0];
    const float* pred_loc  = (const float*)d_in[1];
    const float* gt_conf   = (const float*)d_in[2];
    const float* gt_loc    = (const float*)d_in[3];
    float* out = (float*)d_out;

    int*   pos_buckets = (int*)d_ws;                     // [0, 4096)
    float* row_pos     = (float*)((char*)d_ws + 4096);   // [4096, 4352)
    float* vals        = (float*)((char*)d_ws + 8192);   // [64*8732] floats

    hipMemsetAsync(d_ws, 0, 8192, stream);               // buckets + row_pos
    hipMemsetAsync(d_out, 0, 128 * sizeof(float), stream);

    conf_kernel<<<NB * NANCH / 64, 256, 0, stream>>>(pred_conf, gt_conf, vals,
                                                     pos_buckets, row_pos);
    loc_kernel<<<dim3((NANCH + 255) / 256, NB), 256, 0, stream>>>(pred_loc, gt_loc, out);
    select_kernel<<<NB, 1024, 0, stream>>>(vals, pos_buckets, row_pos, out);
}